// Round 7
// baseline (425.850 us; speedup 1.0000x reference)
//
#include <hip/hip_runtime.h>

// Problem constants (from reference)
constexpr int COLS    = 8;
constexpr int BATCH   = 8192;
constexpr int D       = 128;
constexpr int NUM_EMB = 12;
constexpr int NPAIRS  = 28;

typedef float floatx4 __attribute__((ext_vector_type(4)));

__device__ __forceinline__ float dot4(const floatx4 a, const floatx4 b) {
    return fmaf(a.x, b.x, fmaf(a.y, b.y, fmaf(a.z, b.z, a.w * b.w)));
}

__device__ __forceinline__ floatx4 ld4(const float* p) {
    return *reinterpret_cast<const floatx4*>(p);
}

__device__ __forceinline__ void st4(float* p, const floatx4 v) {
    *reinterpret_cast<floatx4*>(p) = v;
}

__device__ __forceinline__ float softplus01(float x) {
    return 0.01f * ((x > 15.0f) ? x : log1pf(expf(x)));
}

// Block = 256 threads = 4 waves; each 32-lane half-wave owns one batch row.
// Weights staged in LDS ([28][4][128] f32, zero-padded B rows for non-cat):
// the k-loop has exactly 2 VMEM loads (noise) + 4 ds_read_b128 + VALU. No
// arrays in the loop (scratch-proof), no branches (waitcnt-friendly).
__global__ __launch_bounds__(256, 2) void dsnas_kernel(
    const int*   __restrict__ features,   // [COLS, BATCH]
    const float* __restrict__ emb_mean,   // [COLS, NUM_EMB, D]
    const float* __restrict__ emb_std,    // [COLS, NUM_EMB, D]
    const float* __restrict__ W_nc,       // [NPAIRS, 4, 2, D]
    const float* __restrict__ W_cat,      // [NPAIRS, 2, 2*D]
    const float* __restrict__ log_alpha,  // [NPAIRS, 5]
    const float* __restrict__ noise,      // [NPAIRS, 2, BATCH, D]
    float*       __restrict__ out)        // [BATCH, 2]
{
    // Per pair k, 4 rows of 128 floats: [A0 | B0 | A1 | B1].
    //  cat (s==4): straight copy of W_cat[k] (512 floats) -> dot(p,A)+dot(q,B)
    //  non-cat:    [wnc_row0 | 0 | wnc_row1 | 0]          -> dot(c,A)+dot(q,0)
    __shared__ float wlds[NPAIRS * 512];
    __shared__ int   pos_s[NPAIRS];

    const int tid = threadIdx.x;

    // Hard top-1 routing per pair (argmax over 5, first-max wins)
    if (tid < NPAIRS) {
        const float* la = log_alpha + tid * 5;
        float best = la[0];
        int   bi   = 0;
        #pragma unroll
        for (int t = 1; t < 5; ++t) {
            float v = la[t];
            if (v > best) { best = v; bi = t; }
        }
        pos_s[tid] = bi;
    }
    __syncthreads();

    // ---- Stage selected weights into LDS (all 256 threads cooperatively) ----
    // 28 pairs * 128 float4 = 3584 float4 slots; 14 per thread.
    #pragma unroll
    for (int r = 0; r < 14; ++r) {
        const int idx = tid + r * 256;     // float4 slot id
        const int k   = idx >> 7;          // pair (128 f4 per pair)
        const int f   = idx & 127;         // f4 within pair
        const int row = f >> 5;            // 0..3 (32 f4 per row)
        const int c4  = f & 31;            // f4 within row
        const int s   = pos_s[k];
        floatx4 v = {0.0f, 0.0f, 0.0f, 0.0f};
        if (s == 4) {
            v = ld4(W_cat + (size_t)k * 512 + f * 4);
        } else if ((row & 1) == 0) {
            v = ld4(W_nc + (size_t)(k * 4 + s) * 256 + (row >> 1) * 128 + c4 * 4);
        }
        st4(wlds + k * 512 + f * 4, v);
    }

    // Loop-invariant routing masks (computed per-thread, register-resident)
    unsigned cat_mask = 0;
    unsigned long long ops = 0;
    #pragma unroll
    for (int k = 0; k < NPAIRS; ++k) {
        const int s = pos_s[k];
        cat_mask |= (unsigned)(s == 4 ? 1 : 0) << k;
        ops      |= (unsigned long long)(s & 3) << (2 * k);
    }
    __syncthreads();

    const int b    = blockIdx.x * 8 + (tid >> 5);  // one batch row per half-wave
    const int lane = tid & 31;
    const int d0   = lane * 4;                     // 4 consecutive dims per lane

    // Per-column mean + 0.01*softplus(std) for this row's 4 dims, in VGPRs.
    floatx4 Mv[COLS], Sv[COLS];
    #pragma unroll
    for (int i = 0; i < COLS; ++i) {
        const int fi = features[i * BATCH + b];
        const floatx4 m = ld4(emb_mean + ((size_t)(i * NUM_EMB + fi)) * D + d0);
        const floatx4 s = ld4(emb_std  + ((size_t)(i * NUM_EMB + fi)) * D + d0);
        Mv[i] = m;
        floatx4 sp;
        sp.x = softplus01(s.x);
        sp.y = softplus01(s.y);
        sp.z = softplus01(s.z);
        sp.w = softplus01(s.w);
        Sv[i] = sp;
    }

    constexpr int PI[NPAIRS] = {0,0,0,0,0,0,0, 1,1,1,1,1,1, 2,2,2,2,2, 3,3,3,3, 4,4,4, 5,5, 6};
    constexpr int PJ[NPAIRS] = {1,2,3,4,5,6,7, 2,3,4,5,6,7, 3,4,5,6,7, 4,5,6,7, 5,6,7, 6,7, 7};

    const float* nrow = noise + (size_t)b * D + d0;
    constexpr size_t KSTRIDE = (size_t)2 * BATCH * D;  // between pairs k
    constexpr size_t HSTRIDE = (size_t)BATCH * D;      // between halves

    float acc0 = 0.0f, acc1 = 0.0f;

    #pragma unroll
    for (int k = 0; k < NPAIRS; ++k) {
        // The ONLY VMEM in the loop: this pair's two noise vectors.
        const floatx4 n0 = ld4(nrow + (size_t)k * KSTRIDE);
        const floatx4 n1 = ld4(nrow + (size_t)k * KSTRIDE + HSTRIDE);

        // Weights from LDS (both half-waves read the same rows: broadcast-ish)
        const float* wk = wlds + k * 512 + d0;
        const floatx4 A0 = ld4(wk);
        const floatx4 B0 = ld4(wk + 128);
        const floatx4 A1 = ld4(wk + 256);
        const floatx4 B1 = ld4(wk + 384);

        // Reparameterize
        const int i = PI[k];
        const int j = PJ[k];
        floatx4 p, q;
        p.x = fmaf(Sv[i].x, n0.x, Mv[i].x);
        p.y = fmaf(Sv[i].y, n0.y, Mv[i].y);
        p.z = fmaf(Sv[i].z, n0.z, Mv[i].z);
        p.w = fmaf(Sv[i].w, n0.w, Mv[i].w);
        q.x = fmaf(Sv[j].x, n1.x, Mv[j].x);
        q.y = fmaf(Sv[j].y, n1.y, Mv[j].y);
        q.z = fmaf(Sv[j].z, n1.z, Mv[j].z);
        q.w = fmaf(Sv[j].w, n1.w, Mv[j].w);

        // Branchless combine via loop-invariant masks (k is a literal here)
        const bool s4  = (cat_mask >> k) & 1u;
        const int  op  = (int)((ops >> (2 * k)) & 3ull);
        const bool lo  = op < 2;      // {add,mul} vs {max,min}
        const bool ev  = (op & 1) == 0;
        floatx4 c, u;
        c.x = lo ? (ev ? p.x + q.x : p.x * q.x) : (ev ? fmaxf(p.x, q.x) : fminf(p.x, q.x));
        c.y = lo ? (ev ? p.y + q.y : p.y * q.y) : (ev ? fmaxf(p.y, q.y) : fminf(p.y, q.y));
        c.z = lo ? (ev ? p.z + q.z : p.z * q.z) : (ev ? fmaxf(p.z, q.z) : fminf(p.z, q.z));
        c.w = lo ? (ev ? p.w + q.w : p.w * q.w) : (ev ? fmaxf(p.w, q.w) : fminf(p.w, q.w));
        u.x = s4 ? p.x : c.x;
        u.y = s4 ? p.y : c.y;
        u.z = s4 ? p.z : c.z;
        u.w = s4 ? p.w : c.w;

        // B rows are zero for non-cat, so q's contribution vanishes exactly.
        acc0 += dot4(u, A0) + dot4(q, B0);
        acc1 += dot4(u, A1) + dot4(q, B1);
    }

    // Reduce across the 32 lanes of this half-wave
    #pragma unroll
    for (int m = 16; m >= 1; m >>= 1) {
        acc0 += __shfl_xor(acc0, m, 64);
        acc1 += __shfl_xor(acc1, m, 64);
    }

    if (lane == 0) {
        float2 r; r.x = acc0; r.y = acc1;
        *reinterpret_cast<float2*>(out + b * 2) = r;
    }
}

extern "C" void kernel_launch(void* const* d_in, const int* in_sizes, int n_in,
                              void* d_out, int out_size, void* d_ws, size_t ws_size,
                              hipStream_t stream) {
    const int*   features  = (const int*)  d_in[0];
    const float* emb_mean  = (const float*)d_in[1];
    const float* emb_std   = (const float*)d_in[2];
    const float* W_nc      = (const float*)d_in[3];
    const float* W_cat     = (const float*)d_in[4];
    const float* log_alpha = (const float*)d_in[5];
    const float* noise     = (const float*)d_in[6];
    float*       out       = (float*)d_out;

    dim3 grid(BATCH / 8);   // 1024 blocks
    dim3 block(256);        // 4 waves, 8 batch rows/block
    dsnas_kernel<<<grid, block, 0, stream>>>(features, emb_mean, emb_std,
                                             W_nc, W_cat, log_alpha, noise, out);
}